// Round 1
// baseline (19.249 us; speedup 1.0000x reference)
//
#include <hip/hip_runtime.h>

// Problem constants (from reference): x[B,S,H], W*[H,H], b*[H], out[B,H]
#define BB 32
#define SS 1024
#define HH 256
#define SPLITS 16
#define ROWS_PER_BLOCK (SS / SPLITS)  // 64

// ---------------------------------------------------------------------------
// Math note: reference softmaxes over the QUERY axis (axis=1), so
// sum_q attn[b,q,k] == 1 for every (b,k). Then sum_q context = sum_k v.
// Hence out[b,h] = sum_h' Wv[h,h'] * (sum_s x[b,s,h']) + S * bv[h], exactly.
// Only x needs to be read (32 MB); Wq/bq/Wk/bk are provably unused.
// ---------------------------------------------------------------------------

// Kernel A: partial column sums of x over S.
// grid = BB*SPLITS blocks, 256 threads. partials layout: [BB][SPLITS][HH] f32.
__global__ __launch_bounds__(256) void xsum_partial_kernel(
    const float* __restrict__ x, float* __restrict__ partials) {
    const int blk   = blockIdx.x;
    const int b     = blk / SPLITS;
    const int split = blk % SPLITS;
    const int tid   = threadIdx.x;
    const int h4    = tid & 63;   // float4 column group: covers 256 floats
    const int srow  = tid >> 6;   // 0..3 row phase

    const float4* xb = reinterpret_cast<const float4*>(
        x + (size_t)b * SS * HH + (size_t)split * ROWS_PER_BLOCK * HH);

    float4 acc = make_float4(0.f, 0.f, 0.f, 0.f);
    #pragma unroll 4
    for (int r = srow; r < ROWS_PER_BLOCK; r += 4) {
        float4 v = xb[(size_t)r * (HH / 4) + h4];
        acc.x += v.x; acc.y += v.y; acc.z += v.z; acc.w += v.w;
    }

    __shared__ float4 lds[256];
    lds[tid] = acc;
    __syncthreads();
    if (tid < 64) {
        float4 a0 = lds[tid];
        float4 a1 = lds[tid + 64];
        float4 a2 = lds[tid + 128];
        float4 a3 = lds[tid + 192];
        float4 r;
        r.x = (a0.x + a1.x) + (a2.x + a3.x);
        r.y = (a0.y + a1.y) + (a2.y + a3.y);
        r.z = (a0.z + a1.z) + (a2.z + a3.z);
        r.w = (a0.w + a1.w) + (a2.w + a3.w);
        reinterpret_cast<float4*>(
            partials + ((size_t)b * SPLITS + split) * HH)[h4] = r;
    }
}

// Kernel B: reduce partials -> Xsum[b,:] in LDS, then out[b,h] =
// dot(Wv[h,:], Xsum[b,:]) + S*bv[h]. grid = BB blocks, 256 threads.
__global__ __launch_bounds__(256) void out_kernel(
    const float* __restrict__ partials, const float* __restrict__ Wv,
    const float* __restrict__ bv, float* __restrict__ out) {
    const int b = blockIdx.x;
    const int h = threadIdx.x;

    __shared__ float xsum[HH];
    float s = 0.f;
    #pragma unroll
    for (int c = 0; c < SPLITS; ++c)
        s += partials[((size_t)b * SPLITS + c) * HH + h];
    xsum[h] = s;
    __syncthreads();

    const float4* wrow = reinterpret_cast<const float4*>(Wv + (size_t)h * HH);
    const float4* xs   = reinterpret_cast<const float4*>(xsum);
    float acc = (float)SS * bv[h];
    #pragma unroll 8
    for (int i = 0; i < HH / 4; ++i) {
        float4 w  = wrow[i];
        float4 xv = xs[i];
        acc += w.x * xv.x + w.y * xv.y + w.z * xv.z + w.w * xv.w;
    }
    out[(size_t)b * HH + h] = acc;
}

extern "C" void kernel_launch(void* const* d_in, const int* in_sizes, int n_in,
                              void* d_out, int out_size, void* d_ws, size_t ws_size,
                              hipStream_t stream) {
    // setup_inputs order: x, Wq, bq, Wk, bk, Wv, bv
    const float* x  = (const float*)d_in[0];
    const float* Wv = (const float*)d_in[5];
    const float* bv = (const float*)d_in[6];
    float* out = (float*)d_out;
    float* partials = (float*)d_ws;  // BB*SPLITS*HH floats = 512 KB

    xsum_partial_kernel<<<BB * SPLITS, 256, 0, stream>>>(x, partials);
    out_kernel<<<BB, 256, 0, stream>>>(partials, Wv, bv, out);
}